// Round 5
// baseline (381.440 us; speedup 1.0000x reference)
//
#include <hip/hip_runtime.h>

#define NB 256       // batch
#define NT_ 2048     // timesteps
#define DIN 64
#define DH 128
#define HB 64        // h-channels per block (h-split: 2 blocks per batch)
#define TT 32        // time tile
#define NTILES (NT_ / TT)   // 64

// Structure: 4 MFMA waves (each owns one 16-h tile) + 1 scan wave.
// GEMM via v_mfma_f32_16x16x32_bf16 with fp32 -> bf16 hi/lo split.
// Prefetch distance 2 over a 4-buffer xs ring; COUNTED s_waitcnt vmcnt(2)
// (targets loads issued a full tile earlier -> already resident) followed by
// __builtin_amdgcn_s_barrier() — the guide-verified waitcnt+barrier idiom.
// LDS: xs 4*8KB + ffs 2*8KB = 48 KB/block; grid 512 -> 2 blocks/CU (96 KB).

typedef const __attribute__((address_space(1))) void gptr_t;
typedef __attribute__((address_space(3))) void lptr_t;
typedef __attribute__((ext_vector_type(4))) float f32x4;
typedef __attribute__((ext_vector_type(8))) short bf16x8;
typedef __attribute__((ext_vector_type(4))) unsigned int u32x4;

// top-16-bit (bf16 truncation) of f, kept as fp32
__device__ __forceinline__ float hif(float f) {
    return __uint_as_float(__float_as_uint(f) & 0xFFFF0000u);
}
// pack hi16(ev), hi16(od) -> one u32 (ev in low half): v_perm_b32
__device__ __forceinline__ unsigned int pkhi(float ev, float od) {
    return __builtin_amdgcn_perm(__float_as_uint(od), __float_as_uint(ev), 0x07060302u);
}
// 8 floats -> 8 bf16 (truncation)
__device__ __forceinline__ bf16x8 pack_hi8(float4 a, float4 b) {
    union { u32x4 u; bf16x8 v; } t;
    t.u.x = pkhi(a.x, a.y); t.u.y = pkhi(a.z, a.w);
    t.u.z = pkhi(b.x, b.y); t.u.w = pkhi(b.z, b.w);
    return t.v;
}
__device__ __forceinline__ float4 resid4(float4 f) {
    float4 r;
    r.x = f.x - hif(f.x); r.y = f.y - hif(f.y);
    r.z = f.z - hif(f.z); r.w = f.w - hif(f.w);
    return r;
}

__device__ __forceinline__ void scan_tile(const float* ffs_buf, float& mem, float& spk,
                                          float* op, int t0, int lane) {
    #pragma unroll
    for (int tt = 0; tt < TT; ++tt) {
        // read with the C-write XOR swizzle: col = h ^ (((t>>2)&3)<<4)
        float f = ffs_buf[tt * HB + (lane ^ (((tt >> 2) & 3) << 4))];
        mem = fmaf(0.9f, mem, f - spk);
        // sigmoid(5*(mem-1)) = 1/(1+2^(-5*log2e*(mem-1)))
        float e = __builtin_amdgcn_exp2f(-7.213475204444817f * (mem - 1.f));
        spk = __builtin_amdgcn_rcpf(1.f + e);
        op[(size_t)(t0 + tt) * DH] = spk;
    }
}

// stage one 32x64 fp32 x tile (8KB) with 256 threads (waves 0-3), 2 issues each.
// LDS dest is linear; global SOURCE is inverse-swizzled so that LDS[row][c]
// holds x[row][c ^ ((row&7)<<5 bytes)] -> conflict-free A-frag reads.
#define STAGE(DB, IT) { \
    _Pragma("unroll") \
    for (int j = 0; j < 2; ++j) { \
        const int idx = j * 256 + tid; \
        const int row = idx >> 4; \
        const int swf = ((((idx & 15) << 4) ^ ((row & 7) << 5)) >> 2); \
        __builtin_amdgcn_global_load_lds( \
            (gptr_t*)(xb + (size_t)(IT) * TT * DIN + row * DIN + swf), \
            (lptr_t*)(&xs[DB][idx * 4]), 16, 0, 0); \
    } }

__global__ __launch_bounds__(320, 3) void snn_fused_kernel(
    const float* __restrict__ x, const float* __restrict__ W,
    const float* __restrict__ bias, float* __restrict__ out)
{
    __shared__ float xs[4][TT * DIN];   // staged x tiles, 4-deep ring (src-swizzled)
    __shared__ float ffs[2][TT * HB];   // ff tiles (C-layout swizzled)

    const int tid   = threadIdx.x;
    const int wv    = tid >> 6;         // 0..4 (0-3: MFMA, 4: scan)
    const int lane  = tid & 63;
    const int b     = blockIdx.x >> 1;
    const int hhalf = blockIdx.x & 1;

    const float* xb = x + (size_t)b * NT_ * DIN;

    if (wv < 4) {
        // ---------------- producer: MFMA waves ----------------
        const int l15 = lane & 15;
        const int lg  = lane >> 4;           // 0..3
        const int hrow = hhalf * HB + wv * 16 + l15;
        const float bh = bias[hrow];

        // B fragments (W^T slices), hi+lo, resident in VGPRs (16 regs total).
        bf16x8 bhi[2], blo[2];
        #pragma unroll
        for (int kh = 0; kh < 2; ++kh) {
            const float* wp = W + (size_t)hrow * DIN + kh * 32 + lg * 8;
            float4 g0 = *(const float4*)wp;
            float4 g1 = *(const float4*)(wp + 4);
            bhi[kh] = pack_hi8(g0, g1);
            blo[kh] = pack_hi8(resid4(g0), resid4(g1));
        }

        STAGE(0, 0)                          // preload x tiles 0 and 1
        STAGE(1, 1)
        // wait until only the newest 2 loads (tile 1) may be outstanding
        // -> tile 0 resident; vmcnt retires FIFO so older strays are covered.
        asm volatile("s_waitcnt vmcnt(2)" ::: "memory");
        __builtin_amdgcn_s_barrier();        // [barrier 0]

        const int asw = (lane & 7) << 5;     // A-read swizzle key (row&7 == lane&7)
        const int cw  = (wv * 16 + l15) ^ (lg << 4);   // swizzled ffs column

        for (int it = 0; it < NTILES; ++it) {
            const int buf = it & 1;
            if (it + 2 < NTILES) STAGE((it + 2) & 3, it + 2)   // distance-2 prefetch

            f32x4 acc0 = {bh, bh, bh, bh};   // C-tile t=0..15 (bias pre-added)
            f32x4 acc1 = {bh, bh, bh, bh};   // C-tile t=16..31
            #pragma unroll
            for (int kh = 0; kh < 2; ++kh) {
                // A frags: lane reads x[t][kh*32 + lg*8 .. +7], t = ct*16+l15
                const int koff = (kh * 128 + (lg << 5)) ^ asw;
                const char* base = (const char*)xs[it & 3];
                const float4* p0 = (const float4*)(base + l15 * 256 + koff);
                const float4* p1 = (const float4*)(base + (16 + l15) * 256 + koff);
                float4 f0 = p0[0], f1 = p0[1];
                float4 g0 = p1[0], g1 = p1[1];
                bf16x8 a0h = pack_hi8(f0, f1);
                bf16x8 a1h = pack_hi8(g0, g1);
                bf16x8 a0l = pack_hi8(resid4(f0), resid4(f1));
                bf16x8 a1l = pack_hi8(resid4(g0), resid4(g1));
                acc0 = __builtin_amdgcn_mfma_f32_16x16x32_bf16(a0h, bhi[kh], acc0, 0, 0, 0);
                acc1 = __builtin_amdgcn_mfma_f32_16x16x32_bf16(a1h, bhi[kh], acc1, 0, 0, 0);
                acc0 = __builtin_amdgcn_mfma_f32_16x16x32_bf16(a0l, bhi[kh], acc0, 0, 0, 0);
                acc1 = __builtin_amdgcn_mfma_f32_16x16x32_bf16(a1l, bhi[kh], acc1, 0, 0, 0);
                acc0 = __builtin_amdgcn_mfma_f32_16x16x32_bf16(a0h, blo[kh], acc0, 0, 0, 0);
                acc1 = __builtin_amdgcn_mfma_f32_16x16x32_bf16(a1h, blo[kh], acc1, 0, 0, 0);
            }
            // C write: lane holds C[row=lg*4+r][col=l15]; swizzle col by lg
            #pragma unroll
            for (int r = 0; r < 4; ++r) {
                ffs[buf][(lg * 4 + r) * HB + cw]        = acc0[r];
                ffs[buf][(16 + lg * 4 + r) * HB + cw]   = acc1[r];
            }
            // counted wait: only the 2 loads issued THIS tile (for it+2) may
            // remain in flight -> tile it+1 resident for everyone after the
            // barrier. lgkmcnt(0) publishes the ffs ds_writes.
            if (it + 2 < NTILES)
                asm volatile("s_waitcnt vmcnt(2) lgkmcnt(0)" ::: "memory");
            else
                asm volatile("s_waitcnt vmcnt(0) lgkmcnt(0)" ::: "memory");
            __builtin_amdgcn_s_barrier();    // [barrier 1+it] ff tile published
        }
    } else {
        // ---------------- consumer: scan wave ----------------
        float mem = 0.f, spk = 0.f;
        float* op = out + (size_t)b * NT_ * DH + hhalf * HB + lane;

        __builtin_amdgcn_s_barrier();        // [barrier 0]
        for (int it = 0; it < NTILES; ++it) {
            if (it > 0) {
                scan_tile(ffs[(it - 1) & 1], mem, spk, op, (it - 1) * TT, lane);
            }
            __builtin_amdgcn_s_barrier();    // [barrier 1+it]
        }
        // drain: last tile (MFMA waves have exited; no barrier needed)
        scan_tile(ffs[(NTILES - 1) & 1], mem, spk, op, (NTILES - 1) * TT, lane);
    }
}

extern "C" void kernel_launch(void* const* d_in, const int* in_sizes, int n_in,
                              void* d_out, int out_size, void* d_ws, size_t ws_size,
                              hipStream_t stream) {
    const float* x  = (const float*)d_in[0];
    const float* W  = (const float*)d_in[1];
    const float* bb = (const float*)d_in[2];
    float* out = (float*)d_out;
    snn_fused_kernel<<<dim3(NB * 2), dim3(320), 0, stream>>>(x, W, bb, out);
}